// Round 17
// baseline (71.991 us; speedup 1.0000x reference)
//
#include <hip/hip_runtime.h>
#include <hip/hip_bf16.h>
#include <math.h>

#define L_ 2048
#define NN 4096

// ws float offsets (kf/vf/s regions reinterpreted as bf16; sizes shrink, offsets kept)
#define OFF_Q   0u
#define OFF_K   1048576u
#define OFF_V   2097152u
#define OFF_QP  3145728u
#define OFF_KP  3342336u
#define OFF_VP  3538944u
#define OFF_RT  3932160u
#define OFF_S   3981312u

__device__ __forceinline__ float wsum64(float x) {
#pragma unroll
  for (int o = 32; o > 0; o >>= 1) x += __shfl_xor(x, o, 64);
  return x;
}

__device__ __forceinline__ float bf_lo(unsigned u) { return __uint_as_float(u << 16); }
__device__ __forceinline__ float bf_hi(unsigned u) { return __uint_as_float(u & 0xffff0000u); }

// ---------------- Kernel 1: merged projections (16-node tiles, 1024 blocks)
__global__ __launch_bounds__(256) void k_proj(
    const float* __restrict__ hV, const float* __restrict__ X,
    const float* __restrict__ Wq, const float* __restrict__ bq,
    const float* __restrict__ Wkv, const float* __restrict__ bkv,
    const float* __restrict__ Wqp, const float* __restrict__ bqp,
    const float* __restrict__ Wkvp, const float* __restrict__ bkvp,
    float* __restrict__ ws)
{
  __shared__ __align__(16) float hv[16][64];
  __shared__ float lin[16][192];
  __shared__ float rt[16][12];
  const int tid = threadIdx.x;
  const int node0 = blockIdx.x * 16;
  *(float4*)&hv[tid >> 4][(tid & 15) * 4] = *(const float4*)&hV[(size_t)node0*64 + tid*4];
  __syncthreads();

  if (blockIdx.y < 3) {
    const int j = blockIdx.y * 256 + tid;
    const float* Wcol; int stride; float bias;
    if (j < 256) { Wcol = Wq + j; stride = 256; bias = bq[j]; }
    else { const int jj = j - 256; Wcol = Wkv + jj; stride = 512; bias = bkv[jj]; }

    float acc[16];
#pragma unroll
    for (int n = 0; n < 16; ++n) acc[n] = 0.f;
    for (int i = 0; i < 64; i += 4) {
      const float w0 = Wcol[(i+0)*stride];
      const float w1 = Wcol[(i+1)*stride];
      const float w2 = Wcol[(i+2)*stride];
      const float w3 = Wcol[(i+3)*stride];
#pragma unroll
      for (int n = 0; n < 16; ++n) {
        const float4 h4 = *(const float4*)&hv[n][i];
        acc[n] = fmaf(h4.x, w0, fmaf(h4.y, w1, fmaf(h4.z, w2, fmaf(h4.w, w3, acc[n]))));
      }
    }
    float* qf = ws + OFF_Q;
    __hip_bfloat16* kfb = (__hip_bfloat16*)(ws + OFF_K);
    __hip_bfloat16* vfb = (__hip_bfloat16*)(ws + OFF_V);
    if (j < 256) {
#pragma unroll
      for (int n = 0; n < 16; ++n) qf[(size_t)(node0+n)*256 + j] = acc[n] + bias;
    } else {
      const int jj = j - 256; const int h = jj >> 7; const int r = jj & 127;
      __hip_bfloat16* dst = (r < 64) ? (kfb + h*64 + r) : (vfb + h*64 + (r - 64));
#pragma unroll
      for (int n = 0; n < 16; ++n) dst[(size_t)(node0+n)*256] = __float2bfloat16(acc[n] + bias);
    }
    return;
  }

  // ---- pts path
  if (tid < 192) {
    const float* Wcol; int stride; float bias;
    if (tid < 48) { Wcol = Wqp + tid; stride = 48; bias = bqp[tid]; }
    else { Wcol = Wkvp + (tid - 48); stride = 144; bias = bkvp[tid - 48]; }
    float acc[16];
#pragma unroll
    for (int n = 0; n < 16; ++n) acc[n] = 0.f;
    for (int i = 0; i < 64; i += 4) {
      const float w0 = Wcol[(i+0)*stride];
      const float w1 = Wcol[(i+1)*stride];
      const float w2 = Wcol[(i+2)*stride];
      const float w3 = Wcol[(i+3)*stride];
#pragma unroll
      for (int n = 0; n < 16; ++n) {
        const float4 h4 = *(const float4*)&hv[n][i];
        acc[n] = fmaf(h4.x, w0, fmaf(h4.y, w1, fmaf(h4.z, w2, fmaf(h4.w, w3, acc[n]))));
      }
    }
#pragma unroll
    for (int n = 0; n < 16; ++n) lin[n][tid] = acc[n] + bias;
  }
  float* rtw = ws + OFF_RT;
  if (tid < 16) {
    const float* x = X + (size_t)(node0 + tid) * 9;
    const float Nx=x[0]/10.f, Ny=x[1]/10.f, Nz=x[2]/10.f;
    const float Ax=x[3]/10.f, Ay=x[4]/10.f, Az=x[5]/10.f;
    const float Cx=x[6]/10.f, Cy=x[7]/10.f, Cz=x[8]/10.f;
    const float v1x=Cx-Ax, v1y=Cy-Ay, v1z=Cz-Az;
    const float v2x=Nx-Ax, v2y=Ny-Ay, v2z=Nz-Az;
    const float inv1 = 1.f/sqrtf(v1x*v1x+v1y*v1y+v1z*v1z);
    const float e1x=v1x*inv1, e1y=v1y*inv1, e1z=v1z*inv1;
    const float d12 = e1x*v2x+e1y*v2y+e1z*v2z;
    const float u2x=v2x-e1x*d12, u2y=v2y-e1y*d12, u2z=v2z-e1z*d12;
    const float inv2 = 1.f/sqrtf(u2x*u2x+u2y*u2y+u2z*u2z);
    const float e2x=u2x*inv2, e2y=u2y*inv2, e2z=u2z*inv2;
    const float e3x=e1y*e2z-e1z*e2y;
    const float e3y=e1z*e2x-e1x*e2z;
    const float e3z=e1x*e2y-e1y*e2x;
    const float r[12] = {e1x,e2x,e3x, e1y,e2y,e3y, e1z,e2z,e3z, Ax,Ay,Az};
#pragma unroll
    for (int q = 0; q < 12; ++q) { rt[tid][q] = r[q]; rtw[(size_t)(node0+tid)*12 + q] = r[q]; }
  }
  __syncthreads();
  float* qp = ws + OFF_QP;
  float* kp = ws + OFF_KP;
  float* vp = ws + OFF_VP;
  for (int item = tid; item < 1024; item += 256) {
    const int n = item >> 6, m = item & 63;
    const int node = node0 + n;
    float p0, p1, p2; float* dst;
    if (m < 16) {
      p0 = lin[n][m]; p1 = lin[n][16 + m]; p2 = lin[n][32 + m];
      dst = qp + (size_t)node*48 + m*3;
    } else {
      const int mm = m - 16;
      p0 = lin[n][48 + mm]; p1 = lin[n][96 + mm]; p2 = lin[n][144 + mm];
      const int h = mm / 12, pp = mm % 12;
      if (pp < 4) dst = kp + (size_t)node*48 + (h*4+pp)*3;
      else        dst = vp + (size_t)node*96 + (h*8+(pp-4))*3;
    }
    const float gx = rt[n][0]*p0 + rt[n][1]*p1 + rt[n][2]*p2 + rt[n][9];
    const float gy = rt[n][3]*p0 + rt[n][4]*p1 + rt[n][5]*p2 + rt[n][10];
    const float gz = rt[n][6]*p0 + rt[n][7]*p1 + rt[n][8]*p2 + rt[n][11];
    dst[0]=gx; dst[1]=gy; dst[2]=gz;
  }
}

// ---------------- Kernel 2: attention per node -> s(640) in bf16
// LDS: hE + v_pts + Wb + q + sA (~24KB). All redundant global reads dedup'd
// through LDS; single barrier; a-broadcast via same-wave LDS.
__global__ __launch_bounds__(256) void k_attn(
    const float* __restrict__ hE, const int* __restrict__ Eidx,
    const float* __restrict__ maskAtt,
    const float* __restrict__ Wb, const float* __restrict__ bbv,
    const float* __restrict__ hwts,
    float* __restrict__ ws)
{
  __shared__ float sHE[32][65];
  __shared__ __align__(16) float sPV[32][100];
  __shared__ __align__(16) float sA[4][36];
  __shared__ float sWb[256];
  __shared__ __align__(16) float sQ[256];
  const int tid = threadIdx.x;
  // batch-aware XCD swizzle: XCDs 0-3 get batch 0, XCDs 4-7 batch 1
  const int rb = blockIdx.x & 7, qb = blockIdx.x >> 3;
  const int bat = rb >> 2;
  const int node = bat * L_ + (rb & 3) * 512 + qb;
  const int h = tid >> 6, lane = tid & 63;
  const int kk = lane >> 1, c2 = lane & 1;
  const float* qf  = ws + OFF_Q;
  const unsigned short* kfb = (const unsigned short*)(ws + OFF_K);
  const unsigned short* vfb = (const unsigned short*)(ws + OFF_V);
  const float* qpw = ws + OFF_QP;
  const float* kpw = ws + OFF_KP;
  const float* vpw = ws + OFF_VP;
  const float* rtw = ws + OFF_RT;
  __hip_bfloat16* swb = (__hip_bfloat16*)(ws + OFF_S);

  // ---- uniform neighbor indices (block-uniform -> s_load, SGPRs)
  int nbs[32];
#pragma unroll
  for (int u = 0; u < 32; ++u) nbs[u] = bat*L_ + Eidx[(size_t)node*32 + u];

  // ---- staging loads first (ds_writes wait only on these)
  const float4* he4 = (const float4*)(hE + (size_t)node*2048);
  const float4 st0 = he4[tid], st1 = he4[tid + 256];
  float4 pst[3];
#pragma unroll
  for (int i = 0; i < 3; ++i) {
    const int idx = tid + 256*i;
    pst[i] = *(const float4*)(vpw + (size_t)nbs[idx/24]*96 + (idx%24)*4);
  }
  const float wbv = Wb[tid];                          // 1KB, 1 load/thread
  const float qv  = qf[(size_t)node*256 + tid];       // 1KB, 1 load/thread

  // ---- per-lane v gathers (drain under barrier)
  unsigned short vvr[32];
#pragma unroll
  for (int u = 0; u < 32; ++u) vvr[u] = vfb[(size_t)nbs[u]*256 + tid];

  // ---- per-lane k/kp gathers (into regs, consumed post-barrier)
  const int nb = nbs[kk];
  const float mval = maskAtt[(size_t)node*32 + kk];
  const uint4* krow4 = (const uint4*)(kfb + (size_t)nb*256 + h*64 + c2*32);
  const uint4 kb0 = krow4[0], kb1 = krow4[1], kb2 = krow4[2], kb3 = krow4[3];
  const float* kpr = kpw + (size_t)nb*48 + h*12 + c2*6;
  const float2 kp0 = *(const float2*)&kpr[0];
  const float2 kp1 = *(const float2*)&kpr[2];
  const float2 kp2 = *(const float2*)&kpr[4];

  // ---- LDS writes + single barrier
  {
    const int r0 = tid >> 4, c0 = (tid & 15) * 4;
    sHE[r0][c0] = st0.x; sHE[r0][c0+1] = st0.y; sHE[r0][c0+2] = st0.z; sHE[r0][c0+3] = st0.w;
    const int r1 = (tid + 256) >> 4, c1 = ((tid + 256) & 15) * 4;
    sHE[r1][c1] = st1.x; sHE[r1][c1+1] = st1.y; sHE[r1][c1+2] = st1.z; sHE[r1][c1+3] = st1.w;
#pragma unroll
    for (int i = 0; i < 3; ++i) {
      const int idx = tid + 256*i;
      *(float4*)&sPV[idx/24][(idx%24)*4] = pst[i];
    }
    sWb[tid] = wbv;
    sQ[tid] = qv;
  }
  __syncthreads();

  // ---- b-term from LDS (Wb now in LDS)
  float bt = 0.f;
  {
    const float* wbp = &sWb[c2*128 + h];
#pragma unroll
    for (int i = 0; i < 32; ++i)
      bt = fmaf(sHE[kk][c2*32 + i], wbp[i*4], bt);
  }

  // ---- dot (q from LDS broadcast, k in regs)
  float dot = 0.f;
  {
    const float4* q4 = (const float4*)&sQ[h*64 + c2*32];
    const float4 qa0 = q4[0], qa1 = q4[1], qa2 = q4[2], qa3 = q4[3];
    const float4 qa4 = q4[4], qa5 = q4[5], qa6 = q4[6], qa7 = q4[7];
    dot = fmaf(qa0.x, bf_lo(kb0.x), dot); dot = fmaf(qa0.y, bf_hi(kb0.x), dot);
    dot = fmaf(qa0.z, bf_lo(kb0.y), dot); dot = fmaf(qa0.w, bf_hi(kb0.y), dot);
    dot = fmaf(qa1.x, bf_lo(kb0.z), dot); dot = fmaf(qa1.y, bf_hi(kb0.z), dot);
    dot = fmaf(qa1.z, bf_lo(kb0.w), dot); dot = fmaf(qa1.w, bf_hi(kb0.w), dot);
    dot = fmaf(qa2.x, bf_lo(kb1.x), dot); dot = fmaf(qa2.y, bf_hi(kb1.x), dot);
    dot = fmaf(qa2.z, bf_lo(kb1.y), dot); dot = fmaf(qa2.w, bf_hi(kb1.y), dot);
    dot = fmaf(qa3.x, bf_lo(kb1.z), dot); dot = fmaf(qa3.y, bf_hi(kb1.z), dot);
    dot = fmaf(qa3.z, bf_lo(kb1.w), dot); dot = fmaf(qa3.w, bf_hi(kb1.w), dot);
    dot = fmaf(qa4.x, bf_lo(kb2.x), dot); dot = fmaf(qa4.y, bf_hi(kb2.x), dot);
    dot = fmaf(qa4.z, bf_lo(kb2.y), dot); dot = fmaf(qa4.w, bf_hi(kb2.y), dot);
    dot = fmaf(qa5.x, bf_lo(kb2.z), dot); dot = fmaf(qa5.y, bf_hi(kb2.z), dot);
    dot = fmaf(qa5.z, bf_lo(kb2.w), dot); dot = fmaf(qa5.w, bf_hi(kb2.w), dot);
    dot = fmaf(qa6.x, bf_lo(kb3.x), dot); dot = fmaf(qa6.y, bf_hi(kb3.x), dot);
    dot = fmaf(qa6.z, bf_lo(kb3.y), dot); dot = fmaf(qa6.w, bf_hi(kb3.y), dot);
    dot = fmaf(qa7.x, bf_lo(kb3.z), dot); dot = fmaf(qa7.y, bf_hi(kb3.z), dot);
    dot = fmaf(qa7.z, bf_lo(kb3.w), dot); dot = fmaf(qa7.w, bf_hi(kb3.w), dot);
  }

  // ---- pt (point distance)
  float pt = 0.f;
  {
    const float* qpr = qpw + (size_t)node*48 + h*12 + c2*6;
    const float2 qp0 = *(const float2*)&qpr[0];
    const float2 qp1 = *(const float2*)&qpr[2];
    const float2 qp2 = *(const float2*)&qpr[4];
    float d0 = qp0.x - kp0.x, d1 = qp0.y - kp0.y;
    pt = fmaf(d0, d0, fmaf(d1, d1, pt));
    d0 = qp1.x - kp1.x; d1 = qp1.y - kp1.y;
    pt = fmaf(d0, d0, fmaf(d1, d1, pt));
    d0 = qp2.x - kp2.x; d1 = qp2.y - kp2.y;
    pt = fmaf(d0, d0, fmaf(d1, d1, pt));
  }

  // ---- combine + softmax (in-wave)
  {
    dot += __shfl_xor(dot, 1, 64);
    bt  += __shfl_xor(bt, 1, 64);
    pt  += __shfl_xor(pt, 1, 64);
    const float hw = log1pf(expf(hwts[h]));
    const float lg = 0.07216878364870322f*dot
                   + 0.5773502691896258f*(bt + bbv[h])
                   - 0.06804138174397717f*hw*pt
                   + 100000.f*(mval - 1.f);
    float m = lg;
#pragma unroll
    for (int o = 2; o <= 32; o <<= 1) m = fmaxf(m, __shfl_xor(m, o, 64));
    const float e = __expf(lg - m);
    float ssum = e;
#pragma unroll
    for (int o = 2; o <= 32; o <<= 1) ssum += __shfl_xor(ssum, o, 64);
    // a-broadcast via same-wave LDS round-trip (lgkmcnt orders it; no barrier)
    if (c2 == 0) sA[h][kk] = e / ssum;
  }

  // ---- phase 2: pure LDS/register FMA; a read as float4 broadcast
  const int t24 = lane % 24;
  const int pcol = h*24 + t24;
  float o0 = 0.f, o1 = 0.f, op0 = 0.f, op1 = 0.f, g0 = 0.f, g1 = 0.f;
#pragma unroll
  for (int u = 0; u < 32; u += 4) {
    const float4 a4 = *(const float4*)&sA[h][u];
    o0  = fmaf(a4.x, __uint_as_float((unsigned)vvr[u] << 16), o0);
    o1  = fmaf(a4.y, __uint_as_float((unsigned)vvr[u+1] << 16), o1);
    op0 = fmaf(a4.x, sHE[u][lane], op0);
    op1 = fmaf(a4.y, sHE[u+1][lane], op1);
    g0  = fmaf(a4.x, sPV[u][pcol], g0);
    g1  = fmaf(a4.y, sPV[u+1][pcol], g1);
    o0  = fmaf(a4.z, __uint_as_float((unsigned)vvr[u+2] << 16), o0);
    o1  = fmaf(a4.w, __uint_as_float((unsigned)vvr[u+3] << 16), o1);
    op0 = fmaf(a4.z, sHE[u+2][lane], op0);
    op1 = fmaf(a4.w, sHE[u+3][lane], op1);
    g0  = fmaf(a4.z, sPV[u+2][pcol], g0);
    g1  = fmaf(a4.w, sPV[u+3][pcol], g1);
  }
  const float o = o0 + o1, op = op0 + op1, g = g0 + g1;
  __hip_bfloat16* srow = swb + (size_t)node*640;
  srow[tid] = __float2bfloat16(o);
  srow[384 + tid] = __float2bfloat16(op);

  // ---- o_pt transform (unconditional shfls; lanes 0-7 of each wave write)
  const int p = lane & 7;
  const float gx = __shfl(g, 3*p,   64);
  const float gy = __shfl(g, 3*p+1, 64);
  const float gz = __shfl(g, 3*p+2, 64);
  if (lane < 8) {
    const float* rt = rtw + (size_t)node*12;
    const float dx = gx - rt[9], dy = gy - rt[10], dz = gz - rt[11];
    const float l0 = rt[0]*dx + rt[3]*dy + rt[6]*dz;
    const float l1 = rt[1]*dx + rt[4]*dy + rt[7]*dz;
    const float l2 = rt[2]*dx + rt[5]*dy + rt[8]*dz;
    const int o8 = h*8 + p;
    srow[256 + o8] = __float2bfloat16(l0);
    srow[288 + o8] = __float2bfloat16(l1);
    srow[320 + o8] = __float2bfloat16(l2);
    srow[352 + o8] = __float2bfloat16(sqrtf(fmaf(l0,l0,fmaf(l1,l1,l2*l2)) + 1e-8f));
  }
}

// ---------------- Kernel 3: s(bf16)@Wout + LN0 + MLP + LN1 + mask (4-node tiles)
__global__ __launch_bounds__(256) void k_tail(
    const float* __restrict__ hV, const float* __restrict__ maskV,
    const float* __restrict__ Wout, const float* __restrict__ bout,
    const float* __restrict__ ln0g, const float* __restrict__ ln0b,
    const float* __restrict__ Wd1, const float* __restrict__ bd1,
    const float* __restrict__ Wd2, const float* __restrict__ bd2,
    const float* __restrict__ ln1g, const float* __restrict__ ln1b,
    const float* __restrict__ ws, float* __restrict__ out)
{
  __shared__ __align__(16) float sS[4][640];
  __shared__ float sPart[4][4][64];
  __shared__ float sH0[4][64];
  __shared__ float sHid[4][256];
  __shared__ float sY[4][64];
  const int tid = threadIdx.x;
  const int w = tid >> 6, lane = tid & 63;
  const int node0 = blockIdx.x * 4;
  const unsigned short* swb = (const unsigned short*)(ws + OFF_S);
  const uint4* sb4 = (const uint4*)(swb + (size_t)node0*640);
  float* sflat = &sS[0][0];
  for (int idx = tid; idx < 320; idx += 256) {
    const uint4 v = sb4[idx];
    const int base = idx * 8;
    sflat[base+0] = bf_lo(v.x); sflat[base+1] = bf_hi(v.x);
    sflat[base+2] = bf_lo(v.y); sflat[base+3] = bf_hi(v.y);
    sflat[base+4] = bf_lo(v.z); sflat[base+5] = bf_hi(v.z);
    sflat[base+6] = bf_lo(v.w); sflat[base+7] = bf_hi(v.w);
  }
  __syncthreads();
  {
    float acc[4];
#pragma unroll
    for (int n = 0; n < 4; ++n) acc[n] = 0.f;
    for (int i = w*160; i < w*160+160; ++i) {
      const float wv = Wout[i*64 + lane];
#pragma unroll
      for (int n = 0; n < 4; ++n) acc[n] = fmaf(sS[n][i], wv, acc[n]);
    }
#pragma unroll
    for (int n = 0; n < 4; ++n) sPart[w][n][lane] = acc[n];
  }
  __syncthreads();
  {
    const int n = tid >> 6, j = tid & 63;
    const float u = sPart[0][n][j] + sPart[1][n][j] + sPart[2][n][j] + sPart[3][n][j];
    sH0[n][j] = u + bout[j] + hV[(size_t)(node0+n)*64 + j];
  }
  __syncthreads();
  {
    const int n = w;
    const float x = sH0[n][lane];
    const float mu = wsum64(x) * 0.015625f;
    const float dv = x - mu;
    const float var = wsum64(dv*dv) * 0.015625f;
    sH0[n][lane] = dv * rsqrtf(var + 1e-5f) * ln0g[lane] + ln0b[lane];
  }
  __syncthreads();
  {
    float acc[4];
#pragma unroll
    for (int n = 0; n < 4; ++n) acc[n] = 0.f;
    for (int i = 0; i < 64; ++i) {
      const float wv = Wd1[i*256 + tid];
#pragma unroll
      for (int n = 0; n < 4; ++n) acc[n] = fmaf(sH0[n][i], wv, acc[n]);
    }
    const float b1 = bd1[tid];
#pragma unroll
    for (int n = 0; n < 4; ++n) sHid[n][tid] = fmaxf(acc[n] + b1, 0.f);
  }
  __syncthreads();
  {
    float acc[4];
#pragma unroll
    for (int n = 0; n < 4; ++n) acc[n] = 0.f;
    for (int i = w*64; i < w*64+64; ++i) {
      const float wv = Wd2[i*64 + lane];
#pragma unroll
      for (int n = 0; n < 4; ++n) acc[n] = fmaf(sHid[n][i], wv, acc[n]);
    }
#pragma unroll
    for (int n = 0; n < 4; ++n) sPart[w][n][lane] = acc[n];
  }
  __syncthreads();
  {
    const int n = tid >> 6, j = tid & 63;
    const float u = sPart[0][n][j] + sPart[1][n][j] + sPart[2][n][j] + sPart[3][n][j];
    sY[n][j] = u + bd2[j] + sH0[n][j];
  }
  __syncthreads();
  {
    const int n = w;
    const float x = sY[n][lane];
    const float mu = wsum64(x) * 0.015625f;
    const float dv = x - mu;
    const float var = wsum64(dv*dv) * 0.015625f;
    const float hv1 = dv * rsqrtf(var + 1e-5f) * ln1g[lane] + ln1b[lane];
    out[(size_t)(node0+n)*64 + lane] = hv1 * maskV[node0 + n];
  }
}

extern "C" void kernel_launch(void* const* d_in, const int* in_sizes, int n_in,
                              void* d_out, int out_size, void* d_ws, size_t ws_size,
                              hipStream_t stream)
{
  const float* hV   = (const float*)d_in[0];
  const float* hE   = (const float*)d_in[1];
  const int*   Eidx = (const int*)  d_in[2];
  const float* X    = (const float*)d_in[3];
  const float* maskV= (const float*)d_in[4];
  const float* maskA= (const float*)d_in[5];
  const float* Wq   = (const float*)d_in[6];
  const float* bq   = (const float*)d_in[7];
  const float* Wkv  = (const float*)d_in[8];
  const float* bkv  = (const float*)d_in[9];
  const float* Wqp  = (const float*)d_in[10];
  const float* bqp  = (const float*)d_in[11];
  const float* Wkvp = (const float*)d_in[12];
  const float* bkvp = (const float*)d_in[13];
  const float* Wb   = (const float*)d_in[14];
  const float* bbv  = (const float*)d_in[15];
  const float* hwts = (const float*)d_in[16];
  const float* Wout = (const float*)d_in[17];
  const float* bout = (const float*)d_in[18];
  const float* ln0g = (const float*)d_in[19];
  const float* ln0b = (const float*)d_in[20];
  const float* ln1g = (const float*)d_in[21];
  const float* ln1b = (const float*)d_in[22];
  const float* Wd1  = (const float*)d_in[23];
  const float* bd1  = (const float*)d_in[24];
  const float* Wd2  = (const float*)d_in[25];
  const float* bd2  = (const float*)d_in[26];
  float* ws = (float*)d_ws;
  float* out = (float*)d_out;

  k_proj<<<dim3(256, 4), 256, 0, stream>>>(hV, X, Wq, bq, Wkv, bkv,
                                           Wqp, bqp, Wkvp, bkvp, ws);
  k_attn<<<4096, 256, 0, stream>>>(hE, Eidx, maskA, Wb, bbv, hwts, ws);
  k_tail<<<1024, 256, 0, stream>>>(hV, maskV, Wout, bout, ln0g, ln0b,
                                   Wd1, bd1, Wd2, bd2, ln1g, ln1b, ws, out);
}

// Round 18
// 70.095 us; speedup vs baseline: 1.0271x; 1.0271x over previous
//
#include <hip/hip_runtime.h>
#include <hip/hip_bf16.h>
#include <math.h>

#define L_ 2048
#define NN 4096

// ws float offsets (kf/vf/s regions reinterpreted as bf16; sizes shrink, offsets kept)
#define OFF_Q   0u
#define OFF_K   1048576u
#define OFF_V   2097152u
#define OFF_QP  3145728u
#define OFF_KP  3342336u
#define OFF_VP  3538944u
#define OFF_RT  3932160u
#define OFF_S   3981312u

__device__ __forceinline__ float wsum64(float x) {
#pragma unroll
  for (int o = 32; o > 0; o >>= 1) x += __shfl_xor(x, o, 64);
  return x;
}

__device__ __forceinline__ float bf_lo(unsigned u) { return __uint_as_float(u << 16); }
__device__ __forceinline__ float bf_hi(unsigned u) { return __uint_as_float(u & 0xffff0000u); }

// ---------------- Kernel 1: merged projections (16-node tiles, 1024 blocks)
__global__ __launch_bounds__(256) void k_proj(
    const float* __restrict__ hV, const float* __restrict__ X,
    const float* __restrict__ Wq, const float* __restrict__ bq,
    const float* __restrict__ Wkv, const float* __restrict__ bkv,
    const float* __restrict__ Wqp, const float* __restrict__ bqp,
    const float* __restrict__ Wkvp, const float* __restrict__ bkvp,
    float* __restrict__ ws)
{
  __shared__ __align__(16) float hv[16][64];
  __shared__ float lin[16][192];
  __shared__ float rt[16][12];
  const int tid = threadIdx.x;
  const int node0 = blockIdx.x * 16;
  *(float4*)&hv[tid >> 4][(tid & 15) * 4] = *(const float4*)&hV[(size_t)node0*64 + tid*4];
  __syncthreads();

  if (blockIdx.y < 3) {
    const int j = blockIdx.y * 256 + tid;
    const float* Wcol; int stride; float bias;
    if (j < 256) { Wcol = Wq + j; stride = 256; bias = bq[j]; }
    else { const int jj = j - 256; Wcol = Wkv + jj; stride = 512; bias = bkv[jj]; }

    float acc[16];
#pragma unroll
    for (int n = 0; n < 16; ++n) acc[n] = 0.f;
    for (int i = 0; i < 64; i += 4) {
      const float w0 = Wcol[(i+0)*stride];
      const float w1 = Wcol[(i+1)*stride];
      const float w2 = Wcol[(i+2)*stride];
      const float w3 = Wcol[(i+3)*stride];
#pragma unroll
      for (int n = 0; n < 16; ++n) {
        const float4 h4 = *(const float4*)&hv[n][i];
        acc[n] = fmaf(h4.x, w0, fmaf(h4.y, w1, fmaf(h4.z, w2, fmaf(h4.w, w3, acc[n]))));
      }
    }
    float* qf = ws + OFF_Q;
    __hip_bfloat16* kfb = (__hip_bfloat16*)(ws + OFF_K);
    __hip_bfloat16* vfb = (__hip_bfloat16*)(ws + OFF_V);
    if (j < 256) {
#pragma unroll
      for (int n = 0; n < 16; ++n) qf[(size_t)(node0+n)*256 + j] = acc[n] + bias;
    } else {
      const int jj = j - 256; const int h = jj >> 7; const int r = jj & 127;
      __hip_bfloat16* dst = (r < 64) ? (kfb + h*64 + r) : (vfb + h*64 + (r - 64));
#pragma unroll
      for (int n = 0; n < 16; ++n) dst[(size_t)(node0+n)*256] = __float2bfloat16(acc[n] + bias);
    }
    return;
  }

  // ---- pts path
  if (tid < 192) {
    const float* Wcol; int stride; float bias;
    if (tid < 48) { Wcol = Wqp + tid; stride = 48; bias = bqp[tid]; }
    else { Wcol = Wkvp + (tid - 48); stride = 144; bias = bkvp[tid - 48]; }
    float acc[16];
#pragma unroll
    for (int n = 0; n < 16; ++n) acc[n] = 0.f;
    for (int i = 0; i < 64; i += 4) {
      const float w0 = Wcol[(i+0)*stride];
      const float w1 = Wcol[(i+1)*stride];
      const float w2 = Wcol[(i+2)*stride];
      const float w3 = Wcol[(i+3)*stride];
#pragma unroll
      for (int n = 0; n < 16; ++n) {
        const float4 h4 = *(const float4*)&hv[n][i];
        acc[n] = fmaf(h4.x, w0, fmaf(h4.y, w1, fmaf(h4.z, w2, fmaf(h4.w, w3, acc[n]))));
      }
    }
#pragma unroll
    for (int n = 0; n < 16; ++n) lin[n][tid] = acc[n] + bias;
  }
  float* rtw = ws + OFF_RT;
  if (tid < 16) {
    const float* x = X + (size_t)(node0 + tid) * 9;
    const float Nx=x[0]/10.f, Ny=x[1]/10.f, Nz=x[2]/10.f;
    const float Ax=x[3]/10.f, Ay=x[4]/10.f, Az=x[5]/10.f;
    const float Cx=x[6]/10.f, Cy=x[7]/10.f, Cz=x[8]/10.f;
    const float v1x=Cx-Ax, v1y=Cy-Ay, v1z=Cz-Az;
    const float v2x=Nx-Ax, v2y=Ny-Ay, v2z=Nz-Az;
    const float inv1 = 1.f/sqrtf(v1x*v1x+v1y*v1y+v1z*v1z);
    const float e1x=v1x*inv1, e1y=v1y*inv1, e1z=v1z*inv1;
    const float d12 = e1x*v2x+e1y*v2y+e1z*v2z;
    const float u2x=v2x-e1x*d12, u2y=v2y-e1y*d12, u2z=v2z-e1z*d12;
    const float inv2 = 1.f/sqrtf(u2x*u2x+u2y*u2y+u2z*u2z);
    const float e2x=u2x*inv2, e2y=u2y*inv2, e2z=u2z*inv2;
    const float e3x=e1y*e2z-e1z*e2y;
    const float e3y=e1z*e2x-e1x*e2z;
    const float e3z=e1x*e2y-e1y*e2x;
    const float r[12] = {e1x,e2x,e3x, e1y,e2y,e3y, e1z,e2z,e3z, Ax,Ay,Az};
#pragma unroll
    for (int q = 0; q < 12; ++q) { rt[tid][q] = r[q]; rtw[(size_t)(node0+tid)*12 + q] = r[q]; }
  }
  __syncthreads();
  float* qp = ws + OFF_QP;
  float* kp = ws + OFF_KP;
  float* vp = ws + OFF_VP;
  for (int item = tid; item < 1024; item += 256) {
    const int n = item >> 6, m = item & 63;
    const int node = node0 + n;
    float p0, p1, p2; float* dst;
    if (m < 16) {
      p0 = lin[n][m]; p1 = lin[n][16 + m]; p2 = lin[n][32 + m];
      dst = qp + (size_t)node*48 + m*3;
    } else {
      const int mm = m - 16;
      p0 = lin[n][48 + mm]; p1 = lin[n][96 + mm]; p2 = lin[n][144 + mm];
      const int h = mm / 12, pp = mm % 12;
      if (pp < 4) dst = kp + (size_t)node*48 + (h*4+pp)*3;
      else        dst = vp + (size_t)node*96 + (h*8+(pp-4))*3;
    }
    const float gx = rt[n][0]*p0 + rt[n][1]*p1 + rt[n][2]*p2 + rt[n][9];
    const float gy = rt[n][3]*p0 + rt[n][4]*p1 + rt[n][5]*p2 + rt[n][10];
    const float gz = rt[n][6]*p0 + rt[n][7]*p1 + rt[n][8]*p2 + rt[n][11];
    dst[0]=gx; dst[1]=gy; dst[2]=gz;
  }
}

// ---------------- Kernel 2: attention per node -> s(640) in bf16
__global__ __launch_bounds__(256) void k_attn(
    const float* __restrict__ hE, const int* __restrict__ Eidx,
    const float* __restrict__ maskAtt,
    const float* __restrict__ Wb, const float* __restrict__ bbv,
    const float* __restrict__ hwts,
    float* __restrict__ ws)
{
  __shared__ float sHE[32][65];
  __shared__ __align__(16) float sPV[32][100];
  __shared__ __align__(16) float sA[4][36];
  __shared__ float sWb[256];
  __shared__ __align__(16) float sQ[256];
  const int tid = threadIdx.x;
  const int rb = blockIdx.x & 7, qb = blockIdx.x >> 3;
  const int bat = rb >> 2;
  const int node = bat * L_ + (rb & 3) * 512 + qb;
  const int h = tid >> 6, lane = tid & 63;
  const int kk = lane >> 1, c2 = lane & 1;
  const float* qf  = ws + OFF_Q;
  const unsigned short* kfb = (const unsigned short*)(ws + OFF_K);
  const unsigned short* vfb = (const unsigned short*)(ws + OFF_V);
  const float* qpw = ws + OFF_QP;
  const float* kpw = ws + OFF_KP;
  const float* vpw = ws + OFF_VP;
  const float* rtw = ws + OFF_RT;
  __hip_bfloat16* swb = (__hip_bfloat16*)(ws + OFF_S);

  int nbs[32];
#pragma unroll
  for (int u = 0; u < 32; ++u) nbs[u] = bat*L_ + Eidx[(size_t)node*32 + u];

  const float4* he4 = (const float4*)(hE + (size_t)node*2048);
  const float4 st0 = he4[tid], st1 = he4[tid + 256];
  float4 pst[3];
#pragma unroll
  for (int i = 0; i < 3; ++i) {
    const int idx = tid + 256*i;
    pst[i] = *(const float4*)(vpw + (size_t)nbs[idx/24]*96 + (idx%24)*4);
  }
  const float wbv = Wb[tid];
  const float qv  = qf[(size_t)node*256 + tid];

  unsigned short vvr[32];
#pragma unroll
  for (int u = 0; u < 32; ++u) vvr[u] = vfb[(size_t)nbs[u]*256 + tid];

  const int nb = nbs[kk];
  const float mval = maskAtt[(size_t)node*32 + kk];
  const uint4* krow4 = (const uint4*)(kfb + (size_t)nb*256 + h*64 + c2*32);
  const uint4 kb0 = krow4[0], kb1 = krow4[1], kb2 = krow4[2], kb3 = krow4[3];
  const float* kpr = kpw + (size_t)nb*48 + h*12 + c2*6;
  const float2 kp0 = *(const float2*)&kpr[0];
  const float2 kp1 = *(const float2*)&kpr[2];
  const float2 kp2 = *(const float2*)&kpr[4];

  {
    const int r0 = tid >> 4, c0 = (tid & 15) * 4;
    sHE[r0][c0] = st0.x; sHE[r0][c0+1] = st0.y; sHE[r0][c0+2] = st0.z; sHE[r0][c0+3] = st0.w;
    const int r1 = (tid + 256) >> 4, c1 = ((tid + 256) & 15) * 4;
    sHE[r1][c1] = st1.x; sHE[r1][c1+1] = st1.y; sHE[r1][c1+2] = st1.z; sHE[r1][c1+3] = st1.w;
#pragma unroll
    for (int i = 0; i < 3; ++i) {
      const int idx = tid + 256*i;
      *(float4*)&sPV[idx/24][(idx%24)*4] = pst[i];
    }
    sWb[tid] = wbv;
    sQ[tid] = qv;
  }
  __syncthreads();

  float bt = 0.f;
  {
    const float* wbp = &sWb[c2*128 + h];
#pragma unroll
    for (int i = 0; i < 32; ++i)
      bt = fmaf(sHE[kk][c2*32 + i], wbp[i*4], bt);
  }

  float dot = 0.f;
  {
    const float4* q4 = (const float4*)&sQ[h*64 + c2*32];
    const float4 qa0 = q4[0], qa1 = q4[1], qa2 = q4[2], qa3 = q4[3];
    const float4 qa4 = q4[4], qa5 = q4[5], qa6 = q4[6], qa7 = q4[7];
    dot = fmaf(qa0.x, bf_lo(kb0.x), dot); dot = fmaf(qa0.y, bf_hi(kb0.x), dot);
    dot = fmaf(qa0.z, bf_lo(kb0.y), dot); dot = fmaf(qa0.w, bf_hi(kb0.y), dot);
    dot = fmaf(qa1.x, bf_lo(kb0.z), dot); dot = fmaf(qa1.y, bf_hi(kb0.z), dot);
    dot = fmaf(qa1.z, bf_lo(kb0.w), dot); dot = fmaf(qa1.w, bf_hi(kb0.w), dot);
    dot = fmaf(qa2.x, bf_lo(kb1.x), dot); dot = fmaf(qa2.y, bf_hi(kb1.x), dot);
    dot = fmaf(qa2.z, bf_lo(kb1.y), dot); dot = fmaf(qa2.w, bf_hi(kb1.y), dot);
    dot = fmaf(qa3.x, bf_lo(kb1.z), dot); dot = fmaf(qa3.y, bf_hi(kb1.z), dot);
    dot = fmaf(qa3.z, bf_lo(kb1.w), dot); dot = fmaf(qa3.w, bf_hi(kb1.w), dot);
    dot = fmaf(qa4.x, bf_lo(kb2.x), dot); dot = fmaf(qa4.y, bf_hi(kb2.x), dot);
    dot = fmaf(qa4.z, bf_lo(kb2.y), dot); dot = fmaf(qa4.w, bf_hi(kb2.y), dot);
    dot = fmaf(qa5.x, bf_lo(kb2.z), dot); dot = fmaf(qa5.y, bf_hi(kb2.z), dot);
    dot = fmaf(qa5.z, bf_lo(kb2.w), dot); dot = fmaf(qa5.w, bf_hi(kb2.w), dot);
    dot = fmaf(qa6.x, bf_lo(kb3.x), dot); dot = fmaf(qa6.y, bf_hi(kb3.x), dot);
    dot = fmaf(qa6.z, bf_lo(kb3.y), dot); dot = fmaf(qa6.w, bf_hi(kb3.y), dot);
    dot = fmaf(qa7.x, bf_lo(kb3.z), dot); dot = fmaf(qa7.y, bf_hi(kb3.z), dot);
    dot = fmaf(qa7.z, bf_lo(kb3.w), dot); dot = fmaf(qa7.w, bf_hi(kb3.w), dot);
  }

  float pt = 0.f;
  {
    const float* qpr = qpw + (size_t)node*48 + h*12 + c2*6;
    const float2 qp0 = *(const float2*)&qpr[0];
    const float2 qp1 = *(const float2*)&qpr[2];
    const float2 qp2 = *(const float2*)&qpr[4];
    float d0 = qp0.x - kp0.x, d1 = qp0.y - kp0.y;
    pt = fmaf(d0, d0, fmaf(d1, d1, pt));
    d0 = qp1.x - kp1.x; d1 = qp1.y - kp1.y;
    pt = fmaf(d0, d0, fmaf(d1, d1, pt));
    d0 = qp2.x - kp2.x; d1 = qp2.y - kp2.y;
    pt = fmaf(d0, d0, fmaf(d1, d1, pt));
  }

  {
    dot += __shfl_xor(dot, 1, 64);
    bt  += __shfl_xor(bt, 1, 64);
    pt  += __shfl_xor(pt, 1, 64);
    const float hw = log1pf(expf(hwts[h]));
    const float lg = 0.07216878364870322f*dot
                   + 0.5773502691896258f*(bt + bbv[h])
                   - 0.06804138174397717f*hw*pt
                   + 100000.f*(mval - 1.f);
    float m = lg;
#pragma unroll
    for (int o = 2; o <= 32; o <<= 1) m = fmaxf(m, __shfl_xor(m, o, 64));
    const float e = __expf(lg - m);
    float ssum = e;
#pragma unroll
    for (int o = 2; o <= 32; o <<= 1) ssum += __shfl_xor(ssum, o, 64);
    if (c2 == 0) sA[h][kk] = e / ssum;
  }

  const int t24 = lane % 24;
  const int pcol = h*24 + t24;
  float o0 = 0.f, o1 = 0.f, op0 = 0.f, op1 = 0.f, g0 = 0.f, g1 = 0.f;
#pragma unroll
  for (int u = 0; u < 32; u += 4) {
    const float4 a4 = *(const float4*)&sA[h][u];
    o0  = fmaf(a4.x, __uint_as_float((unsigned)vvr[u] << 16), o0);
    o1  = fmaf(a4.y, __uint_as_float((unsigned)vvr[u+1] << 16), o1);
    op0 = fmaf(a4.x, sHE[u][lane], op0);
    op1 = fmaf(a4.y, sHE[u+1][lane], op1);
    g0  = fmaf(a4.x, sPV[u][pcol], g0);
    g1  = fmaf(a4.y, sPV[u+1][pcol], g1);
    o0  = fmaf(a4.z, __uint_as_float((unsigned)vvr[u+2] << 16), o0);
    o1  = fmaf(a4.w, __uint_as_float((unsigned)vvr[u+3] << 16), o1);
    op0 = fmaf(a4.z, sHE[u+2][lane], op0);
    op1 = fmaf(a4.w, sHE[u+3][lane], op1);
    g0  = fmaf(a4.z, sPV[u+2][pcol], g0);
    g1  = fmaf(a4.w, sPV[u+3][pcol], g1);
  }
  const float o = o0 + o1, op = op0 + op1, g = g0 + g1;
  __hip_bfloat16* srow = swb + (size_t)node*640;
  srow[tid] = __float2bfloat16(o);
  srow[384 + tid] = __float2bfloat16(op);

  const int p = lane & 7;
  const float gx = __shfl(g, 3*p,   64);
  const float gy = __shfl(g, 3*p+1, 64);
  const float gz = __shfl(g, 3*p+2, 64);
  if (lane < 8) {
    const float* rt = rtw + (size_t)node*12;
    const float dx = gx - rt[9], dy = gy - rt[10], dz = gz - rt[11];
    const float l0 = rt[0]*dx + rt[3]*dy + rt[6]*dz;
    const float l1 = rt[1]*dx + rt[4]*dy + rt[7]*dz;
    const float l2 = rt[2]*dx + rt[5]*dy + rt[8]*dz;
    const int o8 = h*8 + p;
    srow[256 + o8] = __float2bfloat16(l0);
    srow[288 + o8] = __float2bfloat16(l1);
    srow[320 + o8] = __float2bfloat16(l2);
    srow[352 + o8] = __float2bfloat16(sqrtf(fmaf(l0,l0,fmaf(l1,l1,l2*l2)) + 1e-8f));
  }
}

// ---------------- Kernel 3: s(bf16)@Wout + LN0 + MLP + LN1 + mask
// 512 threads, 4 nodes/block, 1024 blocks; 8-way i-split + b128 LDS reads.
__global__ __launch_bounds__(512) void k_tail(
    const float* __restrict__ hV, const float* __restrict__ maskV,
    const float* __restrict__ Wout, const float* __restrict__ bout,
    const float* __restrict__ ln0g, const float* __restrict__ ln0b,
    const float* __restrict__ Wd1, const float* __restrict__ bd1,
    const float* __restrict__ Wd2, const float* __restrict__ bd2,
    const float* __restrict__ ln1g, const float* __restrict__ ln1b,
    const float* __restrict__ ws, float* __restrict__ out)
{
  __shared__ __align__(16) float sS[4][640];
  __shared__ float sPart[8][4][64];
  __shared__ float sH0[4][64];
  __shared__ float sP2[2][4][256];
  __shared__ float sHid[4][256];
  __shared__ float sY[4][64];
  const int tid = threadIdx.x;
  const int w = tid >> 6, lane = tid & 63;
  const int node0 = blockIdx.x * 4;
  const unsigned short* swb = (const unsigned short*)(ws + OFF_S);
  const uint4* sb4 = (const uint4*)(swb + (size_t)node0*640);
  float* sflat = &sS[0][0];
  if (tid < 320) {
    const uint4 v = sb4[tid];
    const int base = tid * 8;
    sflat[base+0] = bf_lo(v.x); sflat[base+1] = bf_hi(v.x);
    sflat[base+2] = bf_lo(v.y); sflat[base+3] = bf_hi(v.y);
    sflat[base+4] = bf_lo(v.z); sflat[base+5] = bf_hi(v.z);
    sflat[base+6] = bf_lo(v.w); sflat[base+7] = bf_hi(v.w);
  }
  __syncthreads();
  // Wout: 8-way i-split (80 each), float4 LDS reads
  {
    float acc[4];
#pragma unroll
    for (int n = 0; n < 4; ++n) acc[n] = 0.f;
    const int i0 = w * 80;
    for (int i = i0; i < i0 + 80; i += 4) {
      const float w0 = Wout[(i+0)*64 + lane];
      const float w1 = Wout[(i+1)*64 + lane];
      const float w2 = Wout[(i+2)*64 + lane];
      const float w3 = Wout[(i+3)*64 + lane];
#pragma unroll
      for (int n = 0; n < 4; ++n) {
        const float4 s4 = *(const float4*)&sS[n][i];
        acc[n] = fmaf(s4.x, w0, fmaf(s4.y, w1, fmaf(s4.z, w2, fmaf(s4.w, w3, acc[n]))));
      }
    }
#pragma unroll
    for (int n = 0; n < 4; ++n) sPart[w][n][lane] = acc[n];
  }
  __syncthreads();
  if (tid < 256) {
    const int n = tid >> 6, j = tid & 63;
    float u = 0.f;
#pragma unroll
    for (int r = 0; r < 8; ++r) u += sPart[r][n][j];
    sH0[n][j] = u + bout[j] + hV[(size_t)(node0+n)*64 + j];
  }
  __syncthreads();
  if (w < 4) {
    const float x = sH0[w][lane];
    const float mu = wsum64(x) * 0.015625f;
    const float dv = x - mu;
    const float var = wsum64(dv*dv) * 0.015625f;
    sH0[w][lane] = dv * rsqrtf(var + 1e-5f) * ln0g[lane] + ln0b[lane];
  }
  __syncthreads();
  // Wd1: 2-way i-split (32 each)
  {
    const int half = tid >> 8, jj = tid & 255;
    float acc[4];
#pragma unroll
    for (int n = 0; n < 4; ++n) acc[n] = 0.f;
    const int i0 = half * 32;
    for (int i = i0; i < i0 + 32; ++i) {
      const float wv = Wd1[i*256 + jj];
#pragma unroll
      for (int n = 0; n < 4; ++n) acc[n] = fmaf(sH0[n][i], wv, acc[n]);
    }
#pragma unroll
    for (int n = 0; n < 4; ++n) sP2[half][n][jj] = acc[n];
  }
  __syncthreads();
  for (int idx = tid; idx < 1024; idx += 512) {
    const int n = idx >> 8, j = idx & 255;
    sHid[n][j] = fmaxf(sP2[0][n][j] + sP2[1][n][j] + bd1[j], 0.f);
  }
  __syncthreads();
  // Wd2: 8-way i-split (32 each)
  {
    float acc[4];
#pragma unroll
    for (int n = 0; n < 4; ++n) acc[n] = 0.f;
    const int i0 = w * 32;
    for (int i = i0; i < i0 + 32; ++i) {
      const float wv = Wd2[i*64 + lane];
#pragma unroll
      for (int n = 0; n < 4; ++n) acc[n] = fmaf(sHid[n][i], wv, acc[n]);
    }
#pragma unroll
    for (int n = 0; n < 4; ++n) sPart[w][n][lane] = acc[n];
  }
  __syncthreads();
  if (tid < 256) {
    const int n = tid >> 6, j = tid & 63;
    float u = 0.f;
#pragma unroll
    for (int r = 0; r < 8; ++r) u += sPart[r][n][j];
    sY[n][j] = u + bd2[j] + sH0[n][j];
  }
  __syncthreads();
  if (w < 4) {
    const float x = sY[w][lane];
    const float mu = wsum64(x) * 0.015625f;
    const float dv = x - mu;
    const float var = wsum64(dv*dv) * 0.015625f;
    const float hv1 = dv * rsqrtf(var + 1e-5f) * ln1g[lane] + ln1b[lane];
    out[(size_t)(node0+w)*64 + lane] = hv1 * maskV[node0 + w];
  }
}

extern "C" void kernel_launch(void* const* d_in, const int* in_sizes, int n_in,
                              void* d_out, int out_size, void* d_ws, size_t ws_size,
                              hipStream_t stream)
{
  const float* hV   = (const float*)d_in[0];
  const float* hE   = (const float*)d_in[1];
  const int*   Eidx = (const int*)  d_in[2];
  const float* X    = (const float*)d_in[3];
  const float* maskV= (const float*)d_in[4];
  const float* maskA= (const float*)d_in[5];
  const float* Wq   = (const float*)d_in[6];
  const float* bq   = (const float*)d_in[7];
  const float* Wkv  = (const float*)d_in[8];
  const float* bkv  = (const float*)d_in[9];
  const float* Wqp  = (const float*)d_in[10];
  const float* bqp  = (const float*)d_in[11];
  const float* Wkvp = (const float*)d_in[12];
  const float* bkvp = (const float*)d_in[13];
  const float* Wb   = (const float*)d_in[14];
  const float* bbv  = (const float*)d_in[15];
  const float* hwts = (const float*)d_in[16];
  const float* Wout = (const float*)d_in[17];
  const float* bout = (const float*)d_in[18];
  const float* ln0g = (const float*)d_in[19];
  const float* ln0b = (const float*)d_in[20];
  const float* ln1g = (const float*)d_in[21];
  const float* ln1b = (const float*)d_in[22];
  const float* Wd1  = (const float*)d_in[23];
  const float* bd1  = (const float*)d_in[24];
  const float* Wd2  = (const float*)d_in[25];
  const float* bd2  = (const float*)d_in[26];
  float* ws = (float*)d_ws;
  float* out = (float*)d_out;

  k_proj<<<dim3(256, 4), 256, 0, stream>>>(hV, X, Wq, bq, Wkv, bkv,
                                           Wqp, bqp, Wkvp, bkvp, ws);
  k_attn<<<4096, 256, 0, stream>>>(hE, Eidx, maskA, Wb, bbv, hwts, ws);
  k_tail<<<1024, 512, 0, stream>>>(hV, maskV, Wout, bout, ln0g, ln0b,
                                   Wd1, bd1, Wd2, bd2, ln1g, ln1b, ws, out);
}